// Round 3
// baseline (622.368 us; speedup 1.0000x reference)
//
#include <hip/hip_runtime.h>
#include <hip/hip_bf16.h>

#define K_DIM 4096
#define N_DIM 4096
#define M_DIM 4096

#define BM 128
#define BN 128
#define BK 32   // K elems consumed per MFMA stage

typedef __attribute__((ext_vector_type(8))) short bf16x8;   // 8 bf16 in 4 VGPRs
typedef __attribute__((ext_vector_type(4))) float f32x4;
typedef __attribute__((ext_vector_type(8))) unsigned short u16x8;

// ---------- fp32 -> bf16 (round-to-nearest-even) ----------
__device__ __forceinline__ unsigned short f2bf(float f) {
    union { float f; unsigned int u; } v; v.f = f;
    unsigned int u = v.u;
    return (unsigned short)((u + 0x7fffu + ((u >> 16) & 1u)) >> 16);
}

// ---------- fused convert: x and W in one launch ----------
__global__ void cvt2_f32_to_bf16(const float* __restrict__ x,
                                 const float* __restrict__ W,
                                 unsigned short* __restrict__ xb,
                                 unsigned short* __restrict__ wb,
                                 int blocks_each) {
    int b = blockIdx.x;
    const float* src = x;
    unsigned short* dst = xb;
    if (b >= blocks_each) { b -= blocks_each; src = W; dst = wb; }
    const int i = (b * 256 + threadIdx.x) * 8;
    float4 f0 = *(const float4*)(src + i);
    float4 f1 = *(const float4*)(src + i + 4);
    u16x8 o;
    o[0] = f2bf(f0.x); o[1] = f2bf(f0.y); o[2] = f2bf(f0.z); o[3] = f2bf(f0.w);
    o[4] = f2bf(f1.x); o[5] = f2bf(f1.y); o[6] = f2bf(f1.z); o[7] = f2bf(f1.w);
    *(u16x8*)(dst + i) = o;
}

// ---------- per-lane 16-bf16-elem fragment load, optionally converting ----------
template <bool BF16SRC>
__device__ __forceinline__ bf16x8 load_frag(const void* base, size_t elem_off) {
    if constexpr (BF16SRC) {
        return *(const bf16x8*)((const unsigned short*)base + elem_off);
    } else {
        const float* f = (const float*)base + elem_off;
        float4 x0 = *(const float4*)(f + 0);
        float4 x1 = *(const float4*)(f + 4);
        u16x8 o;
        o[0]=f2bf(x0.x); o[1]=f2bf(x0.y); o[2]=f2bf(x0.z); o[3]=f2bf(x0.w);
        o[4]=f2bf(x1.x); o[5]=f2bf(x1.y); o[6]=f2bf(x1.z); o[7]=f2bf(x1.w);
        return (bf16x8)o;
    }
}

// ---------- GEMM: C[M,N] = A[M,K] * B[N,K]^T + bias[N] ----------
// Register-direct: NO LDS, NO barriers. Each wave owns a 64x64 tile (4x4 of
// 16x16x32 MFMA) and loads its own A/B fragments straight from global into
// VGPRs, register-double-buffered with the K-loop unrolled x2 so stage k+1's
// 8 loads are in flight during stage k's 16 MFMAs. The compiler emits
// fine-grained s_waitcnt vmcnt(N) per dependency — never a full drain.
// 2x2 waves per block share A-rows/B-rows pairwise -> L1 absorbs the 2x reuse.
template <bool BF16SRC>
__global__ __launch_bounds__(256, 2) void gemm_reg(
    const void* __restrict__ Aptr, const void* __restrict__ Bptr,
    const float* __restrict__ bias, float* __restrict__ C) {

    const int tid  = threadIdx.x;
    const int wave = tid >> 6;
    const int lane = tid & 63;
    const int l16  = lane & 15;
    const int quad = lane >> 4;

    const int bm = blockIdx.y * BM;
    const int bn = blockIdx.x * BN;
    const int wm = (wave & 1) * 64;
    const int wn = (wave >> 1) * 64;

    // lane's base element offsets (frag t adds t*16 rows; stage adds k)
    const size_t arow = (size_t)(bm + wm + l16) * K_DIM + quad * 8;
    const size_t brow = (size_t)(bn + wn + l16) * K_DIM + quad * 8;

    f32x4 acc[4][4] = {};

    bf16x8 a0[4], b0[4], a1[4], b1[4];

#define LOAD_STAGE(AF, BF, KOFF)                                              \
    _Pragma("unroll") for (int t = 0; t < 4; t++) {                           \
        AF[t] = load_frag<BF16SRC>(Aptr, arow + (size_t)t * 16 * K_DIM + (KOFF)); \
        BF[t] = load_frag<BF16SRC>(Bptr, brow + (size_t)t * 16 * K_DIM + (KOFF)); \
    }

#define MFMA_STAGE(AF, BF)                                                    \
    _Pragma("unroll") for (int i = 0; i < 4; i++)                             \
        _Pragma("unroll") for (int j = 0; j < 4; j++)                         \
            acc[i][j] = __builtin_amdgcn_mfma_f32_16x16x32_bf16(              \
                AF[i], BF[j], acc[i][j], 0, 0, 0);

    LOAD_STAGE(a0, b0, 0)

    for (int k0 = 0; k0 < K_DIM; k0 += 2 * BK) {
        LOAD_STAGE(a1, b1, k0 + BK)     // prefetch stage k0+32
        MFMA_STAGE(a0, b0)              // compute stage k0 (covers the loads)
        if (k0 + 2 * BK < K_DIM) {
            LOAD_STAGE(a0, b0, k0 + 2 * BK)
        }
        MFMA_STAGE(a1, b1)
    }
#undef LOAD_STAGE
#undef MFMA_STAGE

    // epilogue: D[row=quad*4+r][col=l16] per 16x16 tile; fused bias
#pragma unroll
    for (int i = 0; i < 4; i++) {
        const int rbase = bm + wm + i * 16 + quad * 4;
#pragma unroll
        for (int j = 0; j < 4; j++) {
            const int col = bn + wn + j * 16 + l16;
            const float bv = bias[col];
#pragma unroll
            for (int r = 0; r < 4; r++)
                C[(size_t)(rbase + r) * N_DIM + col] = acc[i][j][r] + bv;
        }
    }
}

extern "C" void kernel_launch(void* const* d_in, const int* in_sizes, int n_in,
                              void* d_out, int out_size, void* d_ws, size_t ws_size,
                              hipStream_t stream) {
    const float* x = (const float*)d_in[0];   // [M, K]
    const float* W = (const float*)d_in[1];   // [N, K]
    const float* b = (const float*)d_in[2];   // [N]
    float* out = (float*)d_out;               // [M, N]

    const size_t elems = (size_t)M_DIM * K_DIM;               // == N*K here
    const size_t need  = 2 * elems * sizeof(unsigned short);  // 64 MB

    dim3 grid(N_DIM / BN, M_DIM / BM);
    dim3 block(256);

    if (ws_size >= need) {
        unsigned short* xb = (unsigned short*)d_ws;
        unsigned short* wb = xb + elems;
        const int blocks_each = (int)(elems / (256 * 8));     // 8192
        cvt2_f32_to_bf16<<<2 * blocks_each, 256, 0, stream>>>(x, W, xb, wb, blocks_each);
        gemm_reg<true><<<grid, block, 0, stream>>>(xb, wb, b, out);
    } else {
        gemm_reg<false><<<grid, block, 0, stream>>>(x, W, b, out);
    }
}

// Round 4
// 335.130 us; speedup vs baseline: 1.8571x; 1.8571x over previous
//
#include <hip/hip_runtime.h>
#include <hip/hip_bf16.h>

#define K_DIM 4096
#define N_DIM 4096
#define M_DIM 4096

#define BM 128
#define BN 128
#define BK 32

typedef __attribute__((ext_vector_type(8)))  short bf16x8;    // 8 bf16, 4 VGPRs
typedef __attribute__((ext_vector_type(16))) float f32x16;    // 32x32 MFMA acc
typedef __attribute__((ext_vector_type(8)))  unsigned short u16x8;

// ---------- fp32 -> bf16 (round-to-nearest-even) ----------
__device__ __forceinline__ unsigned short f2bf(float f) {
    union { float f; unsigned int u; } v; v.f = f;
    unsigned int u = v.u;
    return (unsigned short)((u + 0x7fffu + ((u >> 16) & 1u)) >> 16);
}

// ---------- fused convert: x and W in one launch ----------
__global__ void cvt2_f32_to_bf16(const float* __restrict__ x,
                                 const float* __restrict__ W,
                                 unsigned short* __restrict__ xb,
                                 unsigned short* __restrict__ wb,
                                 int blocks_each) {
    int b = blockIdx.x;
    const float* src = x;
    unsigned short* dst = xb;
    if (b >= blocks_each) { b -= blocks_each; src = W; dst = wb; }
    const int i = (b * 256 + threadIdx.x) * 8;
    float4 f0 = *(const float4*)(src + i);
    float4 f1 = *(const float4*)(src + i + 4);
    u16x8 o;
    o[0] = f2bf(f0.x); o[1] = f2bf(f0.y); o[2] = f2bf(f0.z); o[3] = f2bf(f0.w);
    o[4] = f2bf(f1.x); o[5] = f2bf(f1.y); o[6] = f2bf(f1.z); o[7] = f2bf(f1.w);
    *(u16x8*)(dst + i) = o;
}

// ---------- async global->LDS, 16B per lane (dest = uniform base + lane*16) ----------
__device__ __forceinline__ void gl_lds16(const void* g, void* l) {
    __builtin_amdgcn_global_load_lds(
        (const __attribute__((address_space(1))) void*)g,
        (__attribute__((address_space(3))) void*)l,
        16, 0, 0);
}

// ---------- GEMM: C[M,N] = A[M,K] * B[N,K]^T + bias[N] ----------
// R1 single-buffer 2-barrier structure (best measured: 203us) with:
//  * 32x32x16 bf16 MFMA (2495 TF ceiling vs 2176 for 16x16x32; 8 MFMA/stage)
//  * XOR-swizzled LDS slots: row r, global chunk q stored at slot q^((r>>1)&3)
//    -> conflict-free for both the 16-row and 32-row read patterns
//  * XCD-aware block swizzle: 8 XCDs x (16 m-tiles x 8 n-tiles) patches
template <bool BF16SRC>
__global__ __launch_bounds__(256) void gemm_bt(
    const void* __restrict__ Aptr, const void* __restrict__ Bptr,
    const float* __restrict__ bias, float* __restrict__ C) {

    __shared__ __align__(16) unsigned short As[BM * BK];  // 8 KB
    __shared__ __align__(16) unsigned short Bs[BN * BK];  // 8 KB

    const int tid  = threadIdx.x;
    const int wave = tid >> 6;
    const int lane = tid & 63;
    const int r32  = lane & 31;
    const int hi   = lane >> 5;        // 0 or 1

    // XCD swizzle: blocks round-robin across 8 XCDs by dispatch index (heuristic).
    // Give each XCD a 16x8 patch of (m,n) tiles -> per-XCD read set 16+8 tiles.
    const int bid = blockIdx.x;
    const int xcd = bid & 7;
    const int idx = bid >> 3;                              // 0..127
    const int mt  = ((xcd & 1) << 4) + (idx & 15);         // 0..31
    const int nt  = (((xcd >> 1) & 3) << 3) + (idx >> 4);  // 0..31
    const int bm  = mt * BM;
    const int bn  = nt * BN;

    const int wm = (wave & 1) * 64;
    const int wn = (wave >> 1) * 64;

    // staging: lane writes granule 16B*lane at wave base; granule = row(tid>>2),
    // slot(tid&3); source global chunk = slot ^ ((row>>1)&3) = slot ^ ((tid>>3)&3)
    const int srow  = tid >> 2;
    const int skq   = (((tid & 3) ^ ((tid >> 3) & 3))) << 3;
    const int wbase = wave << 9;

    f32x16 acc[2][2] = {};

    auto stage_bf16 = [&](int k0) {
        const unsigned short* A = (const unsigned short*)Aptr;
        const unsigned short* B = (const unsigned short*)Bptr;
        gl_lds16(&A[(size_t)(bm + srow) * K_DIM + k0 + skq],      &As[wbase]);
        gl_lds16(&A[(size_t)(bm + 64 + srow) * K_DIM + k0 + skq], &As[2048 + wbase]);
        gl_lds16(&B[(size_t)(bn + srow) * K_DIM + k0 + skq],      &Bs[wbase]);
        gl_lds16(&B[(size_t)(bn + 64 + srow) * K_DIM + k0 + skq], &Bs[2048 + wbase]);
    };

    auto stage_f32 = [&](int k0) {
        const float* A = (const float*)Aptr;
        const float* B = (const float*)Bptr;
        const int r  = tid >> 1;
        const int q0 = (tid & 1) << 1;
        const int s  = (r >> 1) & 3;
        {
            const float* sp = &A[(size_t)(bm + r) * K_DIM + k0 + (q0 << 3)];
            float4 f0 = *(const float4*)(sp + 0);
            float4 f1 = *(const float4*)(sp + 4);
            float4 f2 = *(const float4*)(sp + 8);
            float4 f3 = *(const float4*)(sp + 12);
            u16x8 o0, o1;
            o0[0]=f2bf(f0.x); o0[1]=f2bf(f0.y); o0[2]=f2bf(f0.z); o0[3]=f2bf(f0.w);
            o0[4]=f2bf(f1.x); o0[5]=f2bf(f1.y); o0[6]=f2bf(f1.z); o0[7]=f2bf(f1.w);
            o1[0]=f2bf(f2.x); o1[1]=f2bf(f2.y); o1[2]=f2bf(f2.z); o1[3]=f2bf(f2.w);
            o1[4]=f2bf(f3.x); o1[5]=f2bf(f3.y); o1[6]=f2bf(f3.z); o1[7]=f2bf(f3.w);
            *(u16x8*)&As[r * BK + ((q0 ^ s) << 3)]       = o0;
            *(u16x8*)&As[r * BK + (((q0 + 1) ^ s) << 3)] = o1;
        }
        {
            const float* sp = &B[(size_t)(bn + r) * K_DIM + k0 + (q0 << 3)];
            float4 f0 = *(const float4*)(sp + 0);
            float4 f1 = *(const float4*)(sp + 4);
            float4 f2 = *(const float4*)(sp + 8);
            float4 f3 = *(const float4*)(sp + 12);
            u16x8 o0, o1;
            o0[0]=f2bf(f0.x); o0[1]=f2bf(f0.y); o0[2]=f2bf(f0.z); o0[3]=f2bf(f0.w);
            o0[4]=f2bf(f1.x); o0[5]=f2bf(f1.y); o0[6]=f2bf(f1.z); o0[7]=f2bf(f1.w);
            o1[0]=f2bf(f2.x); o1[1]=f2bf(f2.y); o1[2]=f2bf(f2.z); o1[3]=f2bf(f2.w);
            o1[4]=f2bf(f3.x); o1[5]=f2bf(f3.y); o1[6]=f2bf(f3.z); o1[7]=f2bf(f3.w);
            *(u16x8*)&Bs[r * BK + ((q0 ^ s) << 3)]       = o0;
            *(u16x8*)&Bs[r * BK + (((q0 + 1) ^ s) << 3)] = o1;
        }
    };

    // read-side: row = (multiple of 32) + r32 -> swizzle = (r32>>1)&3.
    // A-frag (32x32x16): lane holds A[m=r32][k = hi*8 + j] per K=16 half;
    // global chunk for half h is (hi + 2h), read from slot (hi+2h)^sw.
    const int sw = (r32 >> 1) & 3;

    for (int k0 = 0; k0 < K_DIM; k0 += BK) {
        __syncthreads();  // previous compute done before overwriting LDS
        if constexpr (BF16SRC) stage_bf16(k0); else stage_f32(k0);
        __syncthreads();  // staging visible

        bf16x8 af[2][2], bfv[2][2];  // [m/n tile][k half]
#pragma unroll
        for (int t = 0; t < 2; t++)
#pragma unroll
            for (int h = 0; h < 2; h++) {
                const int koff = (((hi + 2 * h) ^ sw)) << 3;
                af[t][h]  = *(const bf16x8*)&As[(wm + t * 32 + r32) * BK + koff];
                bfv[t][h] = *(const bf16x8*)&Bs[(wn + t * 32 + r32) * BK + koff];
            }
#pragma unroll
        for (int h = 0; h < 2; h++)
#pragma unroll
            for (int i = 0; i < 2; i++)
#pragma unroll
                for (int j = 0; j < 2; j++)
                    acc[i][j] = __builtin_amdgcn_mfma_f32_32x32x16_bf16(
                        af[i][h], bfv[j][h], acc[i][j], 0, 0, 0);
    }

    // epilogue: 32x32 C/D layout: col = lane&31, row = (reg&3)+8*(reg>>2)+4*hi
#pragma unroll
    for (int i = 0; i < 2; i++) {
        const int rowb = bm + wm + i * 32 + 4 * hi;
#pragma unroll
        for (int j = 0; j < 2; j++) {
            const int col = bn + wn + j * 32 + r32;
            const float bv = bias[col];
#pragma unroll
            for (int reg = 0; reg < 16; reg++) {
                const int row = rowb + (reg & 3) + 8 * (reg >> 2);
                C[(size_t)row * N_DIM + col] = acc[i][j][reg] + bv;
            }
        }
    }
}

extern "C" void kernel_launch(void* const* d_in, const int* in_sizes, int n_in,
                              void* d_out, int out_size, void* d_ws, size_t ws_size,
                              hipStream_t stream) {
    const float* x = (const float*)d_in[0];   // [M, K]
    const float* W = (const float*)d_in[1];   // [N, K]
    const float* b = (const float*)d_in[2];   // [N]
    float* out = (float*)d_out;               // [M, N]

    const size_t elems = (size_t)M_DIM * K_DIM;               // == N*K here
    const size_t need  = 2 * elems * sizeof(unsigned short);  // 64 MB

    dim3 grid((M_DIM / BM) * (N_DIM / BN));                   // 1024, 1D
    dim3 block(256);

    if (ws_size >= need) {
        unsigned short* xb = (unsigned short*)d_ws;
        unsigned short* wb = xb + elems;
        const int blocks_each = (int)(elems / (256 * 8));     // 8192
        cvt2_f32_to_bf16<<<2 * blocks_each, 256, 0, stream>>>(x, W, xb, wb, blocks_each);
        gemm_bt<true><<<grid, block, 0, stream>>>(xb, wb, b, out);
    } else {
        gemm_bt<false><<<grid, block, 0, stream>>>(x, W, b, out);
    }
}